// Round 3
// baseline (2863.281 us; speedup 1.0000x reference)
//
#include <hip/hip_runtime.h>
#include <math.h>

#define NPTS 3072
#define BLK  256
#define NW   4
#define NSL  8          // slots per lane: 8*64 = 512 >= max class size (~307+-17, +12 sigma)
#define NKB  48         // fallback batches: 48*64 = 3072
#define NCLS 10
#define DIAG_T 1024     // diagnostic replay iterations (this round only)

#pragma clang fp contract(off)

__device__ __forceinline__ unsigned umin32(unsigned a, unsigned b) { return a < b ? a : b; }

// 64-lane min-reduce via DPP butterfly; result valid in lane 63 (R6-R12-proven).
__device__ __forceinline__ unsigned dppmin_u32(unsigned x) {
    unsigned t;
    t = (unsigned)__builtin_amdgcn_update_dpp(-1, (int)x, 0x111, 0xF, 0xF, false); x = x < t ? x : t; // row_shr:1
    t = (unsigned)__builtin_amdgcn_update_dpp(-1, (int)x, 0x112, 0xF, 0xF, false); x = x < t ? x : t; // row_shr:2
    t = (unsigned)__builtin_amdgcn_update_dpp(-1, (int)x, 0x114, 0xF, 0xF, false); x = x < t ? x : t; // row_shr:4
    t = (unsigned)__builtin_amdgcn_update_dpp(-1, (int)x, 0x118, 0xF, 0xF, false); x = x < t ? x : t; // row_shr:8
    t = (unsigned)__builtin_amdgcn_update_dpp(-1, (int)x, 0x142, 0xF, 0xF, false); x = x < t ? x : t; // row_bcast:15
    t = (unsigned)__builtin_amdgcn_update_dpp(-1, (int)x, 0x143, 0xF, 0xF, false); x = x < t ? x : t; // row_bcast:31
    return x;
}

__device__ __forceinline__ float readlanef(float v, int l) {
    return __int_as_float(__builtin_amdgcn_readlane(__float_as_int(v), l));
}

// In-walk sweep over NS live slots (NS = ceil(cnt_c/64), dispatched per walk).
// Slots >= NS hold reload-time poison (ss -> +inf) and are never examined.
template<int NS>
__device__ __forceinline__ void sweep_step(const float (&sxr)[NSL], const float (&syr)[NSL],
                                           const float (&szr)[NSL], const unsigned (&mmr)[NSL],
                                           float pcx, float pcy, float pcz,
                                           unsigned &kbest, unsigned &mbest,
                                           float &bx, float &by, float &bz)
{
    float ss[NS];
    #pragma unroll
    for (int i = 0; i < NS; ++i) {
        float dx = pcx - sxr[i], dy = pcy - syr[i], dz = pcz - szr[i];
        ss[i] = (dx*dx + dy*dy) + dz*dz;   // ref order, contract off
    }
    float m;
    if constexpr (NS == 5)
        m = fminf(fminf(fminf(ss[0], ss[1]), fminf(ss[2], ss[3])), ss[4]);
    else if constexpr (NS == 6)
        m = fminf(fminf(fminf(ss[0], ss[1]), fminf(ss[2], ss[3])), fminf(ss[4], ss[5]));
    else
        m = fminf(fminf(fminf(ss[0], ss[1]), fminf(ss[2], ss[3])),
                  fminf(fminf(ss[4], ss[5]), fminf(ss[6], ss[7])));
    kbest = __float_as_uint(m);            // nonneg floats: bits order == value order
    unsigned mb = 0xFFFFFFFFu;
    #pragma unroll
    for (int i = 0; i < NS; ++i) {
        unsigned ci = (ss[i] == m) ? mmr[i] : 0xFFFFFFFFu;
        mb = umin32(mb, ci);
    }
    mbest = mb;
    bx = sxr[0]; by = syr[0]; bz = szr[0];
    #pragma unroll
    for (int i = 1; i < NS; ++i) {         // metas unique (sentinel != any winner)
        bool w = (mmr[i] == mb);
        bx = w ? sxr[i] : bx; by = w ? syr[i] : by; bz = w ? szr[i] : bz;
    }
}

template<int NS>
__device__ __forceinline__ void poison_step(float (&sxr)[NSL], const unsigned (&mmr)[NSL],
                                            unsigned wm)
{
    #pragma unroll
    for (int i = 0; i < NS; ++i)
        if (mmr[i] == wm) sxr[i] = 3e19f;  // poisoned slot: ss -> +inf
}

__global__ __launch_bounds__(BLK)
void frustum_cluster(const float* __restrict__ pts,
                     const int* __restrict__ lblg,
                     const float* __restrict__ anch,
                     int* __restrict__ out,
                     int* __restrict__ ws)
{
    const int tid  = threadIdx.x;
    const int lane = tid & 63;
    const int wid  = tid >> 6;

    // ---------------- global workspace ----------------
    int*    dlg    = ws + 16;                          // 3072 ints: per-point label
    float4* gstats = (float4*)(ws + 8192);             // per-cluster stats

    // ---------------- LDS ----------------
    __shared__ float4 gpts[NPTS];                      // class-grouped points; epilogue: ordered clusters
    __shared__ unsigned short vor16[NPTS];             // visit order; epilogue: bucket counts
    __shared__ unsigned short startv[NPTS];            // run starts; epilogue: bucket ids, then remap16
    __shared__ float amdxy[NCLS], amdz[NCLS];
    __shared__ unsigned vthr[NCLS], wthr[NCLS];        // sqrt-free compare thresholds
    __shared__ int cntL[NCLS], curL[NCLS], baseL[NCLS];
    __shared__ int cntC[NCLS], curC[NCLS], baseC[NCLS];
    __shared__ int p0s, nclusS;

    if (tid < NCLS) {
        float l = anch[tid*3+0], w = anch[tid*3+1], h = anch[tid*3+2];
        amdxy[tid] = fmaxf(l, w);
        amdz[tid]  = h;
        float r2 = sqrtf((l*l + w*w) + h*h) * 0.5f;    // norm(anchor)/2, ref op order
        // V: largest float bits v with sqrtf(v) <= r2  =>  (sqrtf(s) > r2) == (bits(s) > V)
        unsigned lo = 0u, hi = 0x7F7FFFFFu;
        while (hi - lo > 1u) {
            unsigned mid = lo + ((hi - lo) >> 1);
            if (sqrtf(__uint_as_float(mid)) <= r2) lo = mid; else hi = mid;
        }
        vthr[tid] = lo;
        // W: largest float bits w with sqrtf(w) < r2  =>  (sqrtf(s) < r2) == (bits(s) <= W)
        lo = 0u; hi = 0x7F7FFFFFu;
        while (hi - lo > 1u) {
            unsigned mid = lo + ((hi - lo) >> 1);
            if (sqrtf(__uint_as_float(mid)) < r2) lo = mid; else hi = mid;
        }
        wthr[tid] = lo;
        cntL[tid] = 0; curL[tid] = 0; cntC[tid] = 0; curC[tid] = 0;
    }
    __syncthreads();
    for (int j = tid; j < NPTS; j += BLK) atomicAdd(&cntL[lblg[j]], 1);
    __syncthreads();
    if (tid == 0) { int acc = 0; for (int c = 0; c < NCLS; ++c) { baseL[c] = acc; acc += cntL[c]; } }
    __syncthreads();
    // scatter into class-grouped layout; w = prebaked meta (id<<16 | cls<<12 | pos)
    for (int j = tid; j < NPTS; j += BLK) {
        int c = lblg[j];
        int pos = baseL[c] + atomicAdd(&curL[c], 1);
        float4 e;
        e.x = pts[3*j]; e.y = pts[3*j+1]; e.z = pts[3*j+2];
        e.w = __uint_as_float(((unsigned)j << 16) | ((unsigned)c << 12) | (unsigned)pos);
        gpts[pos] = e;
        if (j == 0) p0s = pos;
    }
    if (tid == 0) startv[0] = 0;
    __syncthreads();   // scatter + p0s visible; waves 1-3 fall through to the join barrier

    // ================= single-wave scan: wave 0, ZERO barriers =================
    if (wid == 0) {
        // lane-parked class constants (readlane fetch at walk reload only)
        float axyL = 0.f, azL = 0.f; int vLn = 0, baseLn = 0, cntLn = 0;
        if (lane < NCLS) {
            axyL = amdxy[lane]; azL = amdz[lane];
            vLn = (int)vthr[lane]; baseLn = baseL[lane]; cntLn = cntL[lane];
        }

        // ===== DIAGNOSTIC (this round only): stripped argmin-core replay =====
        // Replays DIAG_T iterations of the exact in-walk critical path
        // (sweep5 -> 6-step DPP reduce -> ballot/tie -> winner meta+coord
        // broadcast -> poison -> pc update) on class-0 data; results discarded.
        // Purpose: localize the ~1.7k-cycle/iter stall. dur(R3)-dur(R1) =
        // DIAG_T * t_core. No output effect; state kept live via asm volatile.
        {
            int cnt0 = __builtin_amdgcn_readlane(cntLn, 0);
            int cnt5 = cnt0 < 320 ? cnt0 : 320;
            float dxr[NSL], dyr[NSL], dzr[NSL];
            unsigned dmr[NSL];
            float qx = pts[0] + 1.0f, qy = pts[1] - 1.0f, qz = pts[2] + 0.5f;
            int dlive = 0;
            for (int t = 0; t < DIAG_T; ++t) {
                if (dlive <= 0) {                      // re-arm every ~cnt5 iters (like real reloads)
                    #pragma unroll
                    for (int i = 0; i < 5; ++i) {
                        int off = lane + (i << 6);
                        bool in = off < cnt5;
                        float4 e = gpts[in ? off : 0];
                        dxr[i] = in ? e.x : 3e19f;
                        dyr[i] = in ? e.y : 0.f;
                        dzr[i] = in ? e.z : 0.f;
                        dmr[i] = in ? __float_as_uint(e.w) : 0xFFFFFFFFu;
                    }
                    dlive = cnt5 - 1;
                }
                unsigned kb, mb; float bx, by, bz;
                sweep_step<5>(dxr, dyr, dzr, dmr, qx, qy, qz, kb, mb, bx, by, bz);
                unsigned wk = (unsigned)__builtin_amdgcn_readlane((int)dppmin_u32(kb), 63);
                bool cand = (kb == wk);
                unsigned long long msk = __ballot(cand);
                if (msk & (msk - 1)) {
                    unsigned wm2 = (unsigned)__builtin_amdgcn_readlane(
                        (int)dppmin_u32(cand ? mb : 0xFFFFFFFFu), 63);
                    msk = __ballot(cand && mb == wm2);
                }
                int wl = __ffsll((unsigned long long)msk) - 1;
                unsigned wmw = (unsigned)__builtin_amdgcn_readlane((int)mb, wl);
                qx = readlanef(bx, wl); qy = readlanef(by, wl); qz = readlanef(bz, wl);
                #pragma unroll
                for (int i = 0; i < 5; ++i)
                    if (dmr[i] == wmw) dxr[i] = 3e19f;
                dlive -= 1;
            }
            asm volatile("" :: "v"(qx), "v"(qy), "v"(qz));
        }
        // ===== END DIAGNOSTIC =====

        const int p0 = p0s;
        int pos = p0;
        int cls = lblg[0];
        unsigned walked = 1u << cls;
        bool doReload = true;
        int live = 0, base_c = 0, cnt_c = 0, nsC = NSL;
        // slot registers (class points, loop-invariant within a walk); poison x=3e19 -> ss=+inf
        float sxr[NSL], syr[NSL], szr[NSL];
        unsigned mmr[NSL];
        float pcx = pts[0], pcy = pts[1], pcz = pts[2];
        float sx = pcx, sy = pcy, sz = pcz, scnt = 1.0f;
        float icx = pcx, icy = pcy, icz = pcz;
        int lab = 0;
        float amdxy_c = 0.f, amdz_c = 0.f; unsigned Vc = 0;
        // visit-order capture: lane (u&63) holds pos of visit u; flushed 64-wide every 64 steps.
        // lane 0 init = p0 covers u=0 (u==0 mod 64 first recurs at u=64, after the u=63 flush).
        unsigned capv = (unsigned)p0;

        for (int t = 0; t < NPTS-1; ++t) {
            if (doReload) {                            // 10x total: walk start
                base_c = __builtin_amdgcn_readlane(baseLn, cls);
                cnt_c  = __builtin_amdgcn_readlane(cntLn, cls);
                #pragma unroll
                for (int i = 0; i < NSL; ++i) {        // full 8: slots >= nsC stay poisoned
                    int off = lane + (i << 6);
                    int p = base_c + off;
                    bool in = off < cnt_c;
                    float4 e = gpts[in ? p : 0];
                    bool v = in && (p != pos);         // fresh class: only current point visited
                    sxr[i] = v ? e.x : 3e19f;          // poisoned slot: ss -> +inf
                    syr[i] = v ? e.y : 0.f;
                    szr[i] = v ? e.z : 0.f;
                    // R13 BUGFIX: dead slots carried gpts[0]'s real meta -> coords-recovery
                    // aliasing poisoned the winner's coords. Sentinel meta for dead slots.
                    mmr[i] = in ? __float_as_uint(e.w) : 0xFFFFFFFFu;
                }
                amdxy_c = readlanef(axyL, cls); amdz_c = readlanef(azL, cls);
                Vc = (unsigned)__builtin_amdgcn_readlane(vLn, cls);
                live = cnt_c - 1;
                nsC = (cnt_c + 63) >> 6;               // live slots this walk (5 for ~307-pt classes)
                doReload = false;
            }
            unsigned kbest, mbest;
            float bx, by, bz;
            if (live > 0) {
                // in-walk sweep: pure register VALU, only nsC slots examined
                if (nsC <= 5)
                    sweep_step<5>(sxr, syr, szr, mmr, pcx, pcy, pcz, kbest, mbest, bx, by, bz);
                else if (nsC == 6)
                    sweep_step<6>(sxr, syr, szr, mmr, pcx, pcy, pcz, kbest, mbest, bx, by, bz);
                else
                    sweep_step<8>(sxr, syr, szr, mmr, pcx, pcy, pcz, kbest, mbest, bx, by, bz);
            } else {
                // fallback (9x total): nearest point of any un-walked class (pen uniform -> drops)
                kbest = 0xFFFFFFFFu; mbest = 0xFFFFFFFFu; bx = by = bz = 0.f;
                for (int k = 0; k < NKB; ++k) {
                    int p = lane + (k << 6);
                    float4 e = gpts[p];
                    unsigned meta = __float_as_uint(e.w);
                    float dx = pcx - e.x, dy = pcy - e.y, dz = pcz - e.z;
                    float s = (dx*dx + dy*dy) + dz*dz;
                    unsigned key = __float_as_uint(s);
                    bool ok = !((walked >> ((meta >> 12) & 15u)) & 1u);
                    if (ok && (key < kbest || (key == kbest && meta < mbest))) {
                        kbest = key; mbest = meta; bx = e.x; by = e.y; bz = e.z;
                    }
                }
            }
            // in-wave argmin: DPP on key; exact ties -> min meta (orig idx dominates)
            unsigned wk = (unsigned)__builtin_amdgcn_readlane((int)dppmin_u32(kbest), 63);
            bool cand = (kbest == wk);
            unsigned long long msk = __ballot(cand);
            if (msk & (msk - 1)) {
                unsigned wm2 = (unsigned)__builtin_amdgcn_readlane(
                    (int)dppmin_u32(cand ? mbest : 0xFFFFFFFFu), 63);
                msk = __ballot(cand && mbest == wm2);
            }
            int wl = __ffsll((unsigned long long)msk) - 1;
            unsigned wm = (unsigned)__builtin_amdgcn_readlane((int)mbest, wl);
            float pix = readlanef(bx, wl), piy = readlanef(by, wl), piz = readlanef(bz, wl);
            pos = (int)(wm & 0xFFFu);
            int clsE = (int)((wm >> 12) & 15u);
            bool nc;
            if (live > 0) {                            // in-walk: clsE == cls structurally
                float dx = pcx - pix, dy = pcy - piy, dz = pcz - piz;
                nc = (fabsf(dx) > amdxy_c) || (fabsf(dy) > amdxy_c) || (fabsf(dz) > amdz_c);
                nc = nc || (wk > Vc);                  // winner key == bits(s): d > r2 sqrt-free
                float ex = icx - pix, ey = icy - piy, ez = icz - piz;
                float seC = (ex*ex + ey*ey) + ez*ez;
                nc = nc || (__float_as_uint(seC) > Vc);
                live -= 1;
                if (nsC <= 5)      poison_step<5>(sxr, mmr, wm);
                else if (nsC == 6) poison_step<6>(sxr, mmr, wm);
                else               poison_step<8>(sxr, mmr, wm);
            } else {                                   // fallback: clsE != cls -> always new cluster
                nc = true;
                walked |= 1u << clsE;
                cls = clsE;
                doReload = true;
            }
            if (nc) {
                lab += 1;
                if (lane == 0) startv[lab] = (unsigned short)(t + 1);
                sx = pix; sy = piy; sz = piz; scnt = 1.0f;
                icx = pix; icy = piy; icz = piz;       // sx/1 == sx exactly: no divide
            } else {
                sx = sx + pix; sy = sy + piy; sz = sz + piz; scnt = scnt + 1.0f;
                icx = sx / scnt; icy = sy / scnt; icz = sz / scnt;
            }
            {
                int u = t + 1;                         // visit index of this winner
                capv = (lane == (u & 63)) ? (unsigned)pos : capv;
                if ((u & 63) == 63)                    // 48 flushes cover vor16[0..3071]
                    vor16[(u & ~63) + lane] = (unsigned short)capv;
            }
            pcx = pix; pcy = piy; pcz = piz;
        }
        if (lane == 0) nclusS = lab;
    }
    __syncthreads();   // join: waves 1-3 parked here during the scan
    const int nclus = nclusS;

    // ---------------- epilogue (R11/R12-proven, unchanged; gpts untouched by scan) ----------------
    // (a) runs in visit order -> per-cluster stats (bitwise == scan's incremental sums) + dl to global
    for (int c2 = tid; c2 <= nclus; c2 += BLK) {
        int s0 = startv[c2];
        int s1e = (c2 < nclus) ? (int)startv[c2+1] : NPTS;
        float ax = 0.f, ay = 0.f, az = 0.f;
        int clsF = 0;
        for (int s = s0; s < s1e; ++s) {
            float4 e = gpts[vor16[s]];
            unsigned pk = __float_as_uint(e.w);
            if (s == s0) clsF = (int)((pk >> 12) & 15u);
            ax = ax + e.x; ay = ay + e.y; az = az + e.z;
            dlg[pk >> 16] = c2;
        }
        if (c2 < nclus) {
            float fc = (float)(s1e - s0);
            float4 g;
            g.x = ax / fc; g.y = ay / fc; g.z = az / fc;
            g.w = __uint_as_float(((unsigned)(s1e - s0) << 4) | (unsigned)clsF);
            gstats[c2] = g;
        }
    }
    __syncthreads();

    // (a2) bucket counts per class over clusters
    for (int c2 = tid; c2 < nclus; c2 += BLK)
        atomicAdd(&cntC[__float_as_uint(gstats[c2].w) & 15u], 1);
    __syncthreads();
    if (tid == 0) { int acc = 0; for (int c = 0; c < NCLS; ++c) { baseC[c] = acc; acc += cntC[c]; } }
    __syncthreads();

    // (b) scatter clusters into class buckets (vor16 = count, startv = cluster id)
    for (int c2 = tid; c2 < nclus; c2 += BLK) {
        unsigned gw = __float_as_uint(gstats[c2].w);
        int cl = (int)(gw & 15u);
        int slot = baseC[cl] + atomicAdd(&curC[cl], 1);
        vor16[slot]  = (unsigned short)(gw >> 4);
        startv[slot] = (unsigned short)c2;
    }
    __syncthreads();

    // (c) class-local stable rank (counts desc, id asc) -> ordered bucket entries in gpts
    for (int slot = tid; slot < nclus; slot += BLK) {
        int cl = 0;
        #pragma unroll
        for (int q = 1; q < NCLS; ++q) cl += (int)(slot >= baseC[q]);
        int b0 = baseC[cl], b1 = b0 + cntC[cl];
        int cnt = (int)vor16[slot], id = (int)startv[slot];
        int r = 0;
        for (int s2 = b0; s2 < b1; ++s2) {
            int cnt2 = (int)vor16[s2], id2 = (int)startv[s2];
            r += (int)((cnt2 > cnt) || (cnt2 == cnt && id2 < id));
        }
        float4 g = gstats[id];
        float4 oe;
        oe.x = g.x; oe.y = g.y; oe.z = g.z;
        oe.w = __uint_as_float(((unsigned)id << 1) | 1u);   // id | kept-bit (class implicit)
        gpts[b0 + r] = oe;
    }
    __syncthreads();

    // (d) remap16 identity (startv reused)
    unsigned short* remap16 = startv;
    for (int c2 = tid; c2 < NPTS; c2 += BLK) remap16[c2] = (unsigned short)c2;
    __syncthreads();

    // (e) per-class merge: classes independent; wave w handles classes w, w+4, w+8 — zero barriers
    for (int cl = wid; cl < NCLS; cl += NW) {
        int b0 = baseC[cl], b1 = b0 + cntC[cl];
        unsigned Wc = wthr[cl];
        for (int i = b0; i < b1; ++i) {
            float4 ei = gpts[i];
            unsigned wi = __float_as_uint(ei.w);
            if (wi & 1u) {                             // kept -> active absorber
                int orgI = (int)(wi >> 1);
                for (int j = i + 1 + lane; j < b1; j += 64) {
                    float4 ej = gpts[j];
                    unsigned wj = __float_as_uint(ej.w);
                    if (wj & 1u) {
                        float ddx = ej.x - ei.x, ddy = ej.y - ei.y, ddz = ej.z - ei.z;
                        float sdd = (ddx*ddx + ddy*ddy) + ddz*ddz;
                        if (__float_as_uint(sdd) <= Wc) {   // == (sqrtf(sdd) < r2_cl)
                            gpts[j].w = __uint_as_float(wj & ~1u);
                            remap16[wj >> 1] = (unsigned short)orgI;
                        }
                    }
                }
            }
        }
    }
    __syncthreads();

    // (f) final relabel
    for (int p = tid; p < NPTS; p += BLK) out[p] = (int)remap16[dlg[p]];
}

extern "C" void kernel_launch(void* const* d_in, const int* in_sizes, int n_in,
                              void* d_out, int out_size, void* d_ws, size_t ws_size,
                              hipStream_t stream) {
    const float* pts  = (const float*)d_in[0];   // [3072,3] f32
    const int*   lbl  = (const int*)d_in[1];     // [3072] i32
    const float* anch = (const float*)d_in[2];   // [10,3] f32
    frustum_cluster<<<dim3(1), dim3(BLK), 0, stream>>>(pts, lbl, anch,
                                                       (int*)d_out, (int*)d_ws);
}

// Round 4
// 2275.436 us; speedup vs baseline: 1.2583x; 1.2583x over previous
//
#include <hip/hip_runtime.h>
#include <math.h>

#define NPTS 3072
#define BLK  256
#define NW   4
#define NSL  8          // slots per lane: 8*64 = 512 >= max class size (~307+-17, +12 sigma)
#define NKB  48         // fallback batches: 48*64 = 3072
#define NCLS 10

#pragma clang fp contract(off)

__device__ __forceinline__ unsigned umin32(unsigned a, unsigned b) { return a < b ? a : b; }

// 4-step DPP row_shr chain: lanes 15/31/47/63 end with the min of their 16-lane row.
// (old=-1 keeps invalid-source lanes at 0xFFFFFFFF = +inf for the min)
__device__ __forceinline__ unsigned rowmin4_u32(unsigned x) {
    unsigned t;
    t = (unsigned)__builtin_amdgcn_update_dpp(-1, (int)x, 0x111, 0xF, 0xF, false); x = x < t ? x : t; // row_shr:1
    t = (unsigned)__builtin_amdgcn_update_dpp(-1, (int)x, 0x112, 0xF, 0xF, false); x = x < t ? x : t; // row_shr:2
    t = (unsigned)__builtin_amdgcn_update_dpp(-1, (int)x, 0x114, 0xF, 0xF, false); x = x < t ? x : t; // row_shr:4
    t = (unsigned)__builtin_amdgcn_update_dpp(-1, (int)x, 0x118, 0xF, 0xF, false); x = x < t ? x : t; // row_shr:8
    return x;
}

// wave-wide u32 min: 4 DPP steps, then 4 parallel readlanes + scalar min tree
// (R2-validated: replaces the 2 row_bcast hops + lane-63 readlane; same value).
__device__ __forceinline__ unsigned wavemin_u32(unsigned x) {
    unsigned r = rowmin4_u32(x);
    unsigned a = (unsigned)__builtin_amdgcn_readlane((int)r, 15);
    unsigned b = (unsigned)__builtin_amdgcn_readlane((int)r, 31);
    unsigned c = (unsigned)__builtin_amdgcn_readlane((int)r, 47);
    unsigned d = (unsigned)__builtin_amdgcn_readlane((int)r, 63);
    return umin32(umin32(a, b), umin32(c, d));   // uniform -> s_min_u32
}

__device__ __forceinline__ float readlanef(float v, int l) {
    return __int_as_float(__builtin_amdgcn_readlane(__float_as_int(v), l));
}

// In-walk sweep over NS live slots (NS = ceil(cnt_c/64), dispatched per walk).
// Slots >= NS hold reload-time poison (ss -> +inf) and are never examined.
template<int NS>
__device__ __forceinline__ void sweep_step(const float (&sxr)[NSL], const float (&syr)[NSL],
                                           const float (&szr)[NSL], const unsigned (&mmr)[NSL],
                                           float pcx, float pcy, float pcz,
                                           unsigned &kbest, unsigned &mbest,
                                           float &bx, float &by, float &bz)
{
    float ss[NS];
    #pragma unroll
    for (int i = 0; i < NS; ++i) {
        float dx = pcx - sxr[i], dy = pcy - syr[i], dz = pcz - szr[i];
        ss[i] = (dx*dx + dy*dy) + dz*dz;   // ref order, contract off
    }
    float m;
    if constexpr (NS == 5)
        m = fminf(fminf(fminf(ss[0], ss[1]), fminf(ss[2], ss[3])), ss[4]);
    else if constexpr (NS == 6)
        m = fminf(fminf(fminf(ss[0], ss[1]), fminf(ss[2], ss[3])), fminf(ss[4], ss[5]));
    else
        m = fminf(fminf(fminf(ss[0], ss[1]), fminf(ss[2], ss[3])),
                  fminf(fminf(ss[4], ss[5]), fminf(ss[6], ss[7])));
    kbest = __float_as_uint(m);            // nonneg floats: bits order == value order
    unsigned mb = 0xFFFFFFFFu;
    #pragma unroll
    for (int i = 0; i < NS; ++i) {
        unsigned ci = (ss[i] == m) ? mmr[i] : 0xFFFFFFFFu;
        mb = umin32(mb, ci);
    }
    mbest = mb;
    bx = sxr[0]; by = syr[0]; bz = szr[0];
    #pragma unroll
    for (int i = 1; i < NS; ++i) {         // metas unique (sentinel != any winner)
        bool w = (mmr[i] == mb);
        bx = w ? sxr[i] : bx; by = w ? syr[i] : by; bz = w ? szr[i] : bz;
    }
}

template<int NS>
__device__ __forceinline__ void poison_step(float (&sxr)[NSL], const unsigned (&mmr)[NSL],
                                            unsigned wm)
{
    #pragma unroll
    for (int i = 0; i < NS; ++i)
        if (mmr[i] == wm) sxr[i] = 3e19f;  // poisoned slot: ss -> +inf
}

// One in-walk iteration + tail, fully branchless (single basic block).
// Tie handling always-on: second wavemin over candidate metas (metas unique ->
// identical winner to the old branchy tie path). Tail is the R2-validated
// predicated form; startv uses the running cluster-start su (rewrites the same
// value when !nc). vor16 row-write unconditional (final write of a row is the
// complete one). #pragma unroll 2 at the call sites lets the scheduler overlap
// iter t's tail with iter t+1's sweep (independent given pc+poison).
#define WALK_INNER(NS)                                                          \
    _Pragma("unroll 2")                                                         \
    for (int k = 0; k < iters; ++k) {                                           \
        unsigned kbest, mbest; float bx, by, bz;                                \
        sweep_step<NS>(sxr, syr, szr, mmr, pcx, pcy, pcz, kbest, mbest, bx, by, bz); \
        unsigned wk = wavemin_u32(kbest);                                       \
        bool cand = (kbest == wk);                                              \
        unsigned wm = wavemin_u32(cand ? mbest : 0xFFFFFFFFu);                  \
        unsigned long long msk = __ballot(cand && (mbest == wm));               \
        int wl = __ffsll((unsigned long long)msk) - 1;                          \
        float pix = readlanef(bx, wl), piy = readlanef(by, wl), piz = readlanef(bz, wl); \
        pos = (int)(wm & 0xFFFu);                                               \
        poison_step<NS>(sxr, mmr, wm);                                          \
        float dx = pcx - pix, dy = pcy - piy, dz = pcz - piz;                   \
        bool a1 = (fabsf(dx) > amdxy_c) | (fabsf(dy) > amdxy_c) | (fabsf(dz) > amdz_c); \
        float ex = icx - pix, ey = icy - piy, ez = icz - piz;                   \
        float seC = (ex*ex + ey*ey) + ez*ez;                                    \
        bool nc = a1 | (wk > Vc) | (__float_as_uint(seC) > Vc);                 \
        lab += (int)nc;                                                         \
        su = nc ? u : su;                                                       \
        *((lane == 0) ? &startv[lab] : &sdump[lane]) = (unsigned short)su;      \
        float ns2 = nc ? 1.0f : (scnt + 1.0f);                                  \
        sx = nc ? pix : (sx + pix);                                             \
        sy = nc ? piy : (sy + piy);                                             \
        sz = nc ? piz : (sz + piz);                                             \
        scnt = ns2;                                                             \
        icx = sx / ns2; icy = sy / ns2; icz = sz / ns2;   /* x/1.0 == x on nc */ \
        capv = (lane == (u & 63)) ? (unsigned)pos : capv;                       \
        vor16[(u & ~63) + lane] = (unsigned short)capv;                         \
        pcx = pix; pcy = piy; pcz = piz;                                        \
        ++u;                                                                    \
    }

__global__ __launch_bounds__(BLK)
void frustum_cluster(const float* __restrict__ pts,
                     const int* __restrict__ lblg,
                     const float* __restrict__ anch,
                     int* __restrict__ out,
                     int* __restrict__ ws)
{
    const int tid  = threadIdx.x;
    const int lane = tid & 63;
    const int wid  = tid >> 6;

    // ---------------- global workspace ----------------
    int*    dlg    = ws + 16;                          // 3072 ints: per-point label
    float4* gstats = (float4*)(ws + 8192);             // per-cluster stats

    // ---------------- LDS ----------------
    __shared__ float4 gpts[NPTS];                      // class-grouped points; epilogue: ordered clusters
    __shared__ unsigned short vor16[NPTS];             // visit order; epilogue: bucket counts
    __shared__ unsigned short startv[NPTS];            // run starts; epilogue: bucket ids, then remap16
    __shared__ unsigned short sdump[64];               // dummy target for predicated startv writes
    __shared__ float amdxy[NCLS], amdz[NCLS];
    __shared__ unsigned vthr[NCLS], wthr[NCLS];        // sqrt-free compare thresholds
    __shared__ int cntL[NCLS], curL[NCLS], baseL[NCLS];
    __shared__ int cntC[NCLS], curC[NCLS], baseC[NCLS];
    __shared__ int p0s, nclusS;

    if (tid < NCLS) {
        float l = anch[tid*3+0], w = anch[tid*3+1], h = anch[tid*3+2];
        amdxy[tid] = fmaxf(l, w);
        amdz[tid]  = h;
        float r2 = sqrtf((l*l + w*w) + h*h) * 0.5f;    // norm(anchor)/2, ref op order
        // V: largest float bits v with sqrtf(v) <= r2  =>  (sqrtf(s) > r2) == (bits(s) > V)
        unsigned lo = 0u, hi = 0x7F7FFFFFu;
        while (hi - lo > 1u) {
            unsigned mid = lo + ((hi - lo) >> 1);
            if (sqrtf(__uint_as_float(mid)) <= r2) lo = mid; else hi = mid;
        }
        vthr[tid] = lo;
        // W: largest float bits w with sqrtf(w) < r2  =>  (sqrtf(s) < r2) == (bits(s) <= W)
        lo = 0u; hi = 0x7F7FFFFFu;
        while (hi - lo > 1u) {
            unsigned mid = lo + ((hi - lo) >> 1);
            if (sqrtf(__uint_as_float(mid)) < r2) lo = mid; else hi = mid;
        }
        wthr[tid] = lo;
        cntL[tid] = 0; curL[tid] = 0; cntC[tid] = 0; curC[tid] = 0;
    }
    __syncthreads();
    for (int j = tid; j < NPTS; j += BLK) atomicAdd(&cntL[lblg[j]], 1);
    __syncthreads();
    if (tid == 0) { int acc = 0; for (int c = 0; c < NCLS; ++c) { baseL[c] = acc; acc += cntL[c]; } }
    __syncthreads();
    // scatter into class-grouped layout; w = prebaked meta (id<<16 | cls<<12 | pos)
    for (int j = tid; j < NPTS; j += BLK) {
        int c = lblg[j];
        int pos = baseL[c] + atomicAdd(&curL[c], 1);
        float4 e;
        e.x = pts[3*j]; e.y = pts[3*j+1]; e.z = pts[3*j+2];
        e.w = __uint_as_float(((unsigned)j << 16) | ((unsigned)c << 12) | (unsigned)pos);
        gpts[pos] = e;
        if (j == 0) p0s = pos;
    }
    if (tid == 0) startv[0] = 0;
    __syncthreads();   // scatter + p0s visible; waves 1-3 fall through to the join barrier

    // ================= single-wave scan: wave 0, ZERO barriers =================
    if (wid == 0) {
        // lane-parked class constants (readlane fetch at walk start only)
        float axyL = 0.f, azL = 0.f; int vLn = 0, baseLn = 0, cntLn = 0;
        if (lane < NCLS) {
            axyL = amdxy[lane]; azL = amdz[lane];
            vLn = (int)vthr[lane]; baseLn = baseL[lane]; cntLn = cntL[lane];
        }
        const int p0 = p0s;
        int pos = p0;
        int cls = lblg[0];
        unsigned walked = 1u << cls;
        // slot registers (class points, loop-invariant within a walk); poison x=3e19 -> ss=+inf
        float sxr[NSL], syr[NSL], szr[NSL];
        unsigned mmr[NSL];
        float pcx = pts[0], pcy = pts[1], pcz = pts[2];
        float sx = pcx, sy = pcy, sz = pcz, scnt = 1.0f;
        float icx = pcx, icy = pcy, icz = pcz;
        int lab = 0;
        int su  = 0;                                   // running cluster-start visit index
        // visit-order capture: lane (u&63) holds pos of visit u; row written every iter
        // (final write of a row is the complete one). lane-0 init = p0 covers visit 0.
        unsigned capv = (unsigned)p0;
        int u = 1;                                     // next visit index

        for (int wix = 0; wix < NCLS; ++wix) {         // max 10 walks
            // ---- walk reload: class cls, excluding current pos ----
            int base_c = __builtin_amdgcn_readlane(baseLn, cls);
            int cnt_c  = __builtin_amdgcn_readlane(cntLn, cls);
            #pragma unroll
            for (int i = 0; i < NSL; ++i) {            // full 8: slots >= nsC stay poisoned
                int off = lane + (i << 6);
                int p = base_c + off;
                bool in = off < cnt_c;
                float4 e = gpts[in ? p : 0];
                bool v = in && (p != pos);             // fresh class: only current point visited
                sxr[i] = v ? e.x : 3e19f;              // poisoned slot: ss -> +inf
                syr[i] = v ? e.y : 0.f;
                szr[i] = v ? e.z : 0.f;
                // R13 BUGFIX: dead slots carry sentinel meta (never matches a winner)
                mmr[i] = in ? __float_as_uint(e.w) : 0xFFFFFFFFu;
            }
            float amdxy_c = readlanef(axyL, cls), amdz_c = readlanef(azL, cls);
            unsigned Vc = (unsigned)__builtin_amdgcn_readlane(vLn, cls);
            int nsC = (cnt_c + 63) >> 6;               // live slots this walk (5 for ~307-pt classes)
            int iters = cnt_c - 1;

            // ---- inner loop: single-block branchless iterations ----
            if (nsC <= 5)      { WALK_INNER(5) }
            else if (nsC == 6) { WALK_INNER(6) }
            else               { WALK_INNER(8) }

            if (u >= NPTS) break;

            // ---- fallback (9x total): nearest point of any un-walked class ----
            {
                unsigned kbest = 0xFFFFFFFFu, mbest = 0xFFFFFFFFu;
                float bx = 0.f, by = 0.f, bz = 0.f;
                for (int k2 = 0; k2 < NKB; ++k2) {
                    int p = lane + (k2 << 6);
                    float4 e = gpts[p];
                    unsigned meta = __float_as_uint(e.w);
                    float dx = pcx - e.x, dy = pcy - e.y, dz = pcz - e.z;
                    float s = (dx*dx + dy*dy) + dz*dz;
                    unsigned key = __float_as_uint(s);
                    bool ok = !((walked >> ((meta >> 12) & 15u)) & 1u);
                    if (ok && (key < kbest || (key == kbest && meta < mbest))) {
                        kbest = key; mbest = meta; bx = e.x; by = e.y; bz = e.z;
                    }
                }
                unsigned wk = wavemin_u32(kbest);
                bool cand = (kbest == wk);
                unsigned wm = wavemin_u32(cand ? mbest : 0xFFFFFFFFu);
                unsigned long long msk = __ballot(cand && (mbest == wm));
                int wl = __ffsll((unsigned long long)msk) - 1;
                float pix = readlanef(bx, wl), piy = readlanef(by, wl), piz = readlanef(bz, wl);
                pos = (int)(wm & 0xFFFu);
                cls = (int)((wm >> 12) & 15u);
                walked |= 1u << cls;
                // nc == true tail (new cluster, new class)
                lab += 1;
                su = u;
                if (lane == 0) startv[lab] = (unsigned short)u;
                sx = pix; sy = piy; sz = piz; scnt = 1.0f;
                icx = pix; icy = piy; icz = piz;       // sx/1 == sx exactly
                capv = (lane == (u & 63)) ? (unsigned)pos : capv;
                vor16[(u & ~63) + lane] = (unsigned short)capv;
                pcx = pix; pcy = piy; pcz = piz;
                ++u;
            }
        }
        if (lane == 0) nclusS = lab;
    }
    __syncthreads();   // join: waves 1-3 parked here during the scan
    const int nclus = nclusS;

    // ---------------- epilogue (R11/R12-proven, unchanged; gpts untouched by scan) ----------------
    // (a) runs in visit order -> per-cluster stats (bitwise == scan's incremental sums) + dl to global
    for (int c2 = tid; c2 <= nclus; c2 += BLK) {
        int s0 = startv[c2];
        int s1e = (c2 < nclus) ? (int)startv[c2+1] : NPTS;
        float ax = 0.f, ay = 0.f, az = 0.f;
        int clsF = 0;
        for (int s = s0; s < s1e; ++s) {
            float4 e = gpts[vor16[s]];
            unsigned pk = __float_as_uint(e.w);
            if (s == s0) clsF = (int)((pk >> 12) & 15u);
            ax = ax + e.x; ay = ay + e.y; az = az + e.z;
            dlg[pk >> 16] = c2;
        }
        if (c2 < nclus) {
            float fc = (float)(s1e - s0);
            float4 g;
            g.x = ax / fc; g.y = ay / fc; g.z = az / fc;
            g.w = __uint_as_float(((unsigned)(s1e - s0) << 4) | (unsigned)clsF);
            gstats[c2] = g;
        }
    }
    __syncthreads();

    // (a2) bucket counts per class over clusters
    for (int c2 = tid; c2 < nclus; c2 += BLK)
        atomicAdd(&cntC[__float_as_uint(gstats[c2].w) & 15u], 1);
    __syncthreads();
    if (tid == 0) { int acc = 0; for (int c = 0; c < NCLS; ++c) { baseC[c] = acc; acc += cntC[c]; } }
    __syncthreads();

    // (b) scatter clusters into class buckets (vor16 = count, startv = cluster id)
    for (int c2 = tid; c2 < nclus; c2 += BLK) {
        unsigned gw = __float_as_uint(gstats[c2].w);
        int cl = (int)(gw & 15u);
        int slot = baseC[cl] + atomicAdd(&curC[cl], 1);
        vor16[slot]  = (unsigned short)(gw >> 4);
        startv[slot] = (unsigned short)c2;
    }
    __syncthreads();

    // (c) class-local stable rank (counts desc, id asc) -> ordered bucket entries in gpts
    for (int slot = tid; slot < nclus; slot += BLK) {
        int cl = 0;
        #pragma unroll
        for (int q = 1; q < NCLS; ++q) cl += (int)(slot >= baseC[q]);
        int b0 = baseC[cl], b1 = b0 + cntC[cl];
        int cnt = (int)vor16[slot], id = (int)startv[slot];
        int r = 0;
        for (int s2 = b0; s2 < b1; ++s2) {
            int cnt2 = (int)vor16[s2], id2 = (int)startv[s2];
            r += (int)((cnt2 > cnt) || (cnt2 == cnt && id2 < id));
        }
        float4 g = gstats[id];
        float4 oe;
        oe.x = g.x; oe.y = g.y; oe.z = g.z;
        oe.w = __uint_as_float(((unsigned)id << 1) | 1u);   // id | kept-bit (class implicit)
        gpts[b0 + r] = oe;
    }
    __syncthreads();

    // (d) remap16 identity (startv reused)
    unsigned short* remap16 = startv;
    for (int c2 = tid; c2 < NPTS; c2 += BLK) remap16[c2] = (unsigned short)c2;
    __syncthreads();

    // (e) per-class merge: classes independent; wave w handles classes w, w+4, w+8 — zero barriers
    for (int cl = wid; cl < NCLS; cl += NW) {
        int b0 = baseC[cl], b1 = b0 + cntC[cl];
        unsigned Wc = wthr[cl];
        for (int i = b0; i < b1; ++i) {
            float4 ei = gpts[i];
            unsigned wi = __float_as_uint(ei.w);
            if (wi & 1u) {                             // kept -> active absorber
                int orgI = (int)(wi >> 1);
                for (int j = i + 1 + lane; j < b1; j += 64) {
                    float4 ej = gpts[j];
                    unsigned wj = __float_as_uint(ej.w);
                    if (wj & 1u) {
                        float ddx = ej.x - ei.x, ddy = ej.y - ei.y, ddz = ej.z - ei.z;
                        float sdd = (ddx*ddx + ddy*ddy) + ddz*ddz;
                        if (__float_as_uint(sdd) <= Wc) {   // == (sqrtf(sdd) < r2_cl)
                            gpts[j].w = __uint_as_float(wj & ~1u);
                            remap16[wj >> 1] = (unsigned short)orgI;
                        }
                    }
                }
            }
        }
    }
    __syncthreads();

    // (f) final relabel
    for (int p = tid; p < NPTS; p += BLK) out[p] = (int)remap16[dlg[p]];
}

extern "C" void kernel_launch(void* const* d_in, const int* in_sizes, int n_in,
                              void* d_out, int out_size, void* d_ws, size_t ws_size,
                              hipStream_t stream) {
    const float* pts  = (const float*)d_in[0];   // [3072,3] f32
    const int*   lbl  = (const int*)d_in[1];     // [3072] i32
    const float* anch = (const float*)d_in[2];   // [10,3] f32
    frustum_cluster<<<dim3(1), dim3(BLK), 0, stream>>>(pts, lbl, anch,
                                                       (int*)d_out, (int*)d_ws);
}

// Round 5
// 2255.043 us; speedup vs baseline: 1.2697x; 1.0090x over previous
//
#include <hip/hip_runtime.h>
#include <math.h>

#define NPTS 3072
#define BLK  256
#define NW   4
#define NSL  8          // slots per lane: 8*64 = 512 >= max class size (~307+-17, +12 sigma)
#define NKB  48         // fallback batches: 48*64 = 3072
#define NCLS 10

#pragma clang fp contract(off)

__device__ __forceinline__ unsigned umin32(unsigned a, unsigned b) { return a < b ? a : b; }

// 4-step DPP row_shr chain: lanes 15/31/47/63 end with the min of their 16-lane row.
// (old=-1 keeps invalid-source lanes at 0xFFFFFFFF = +inf for the min)
__device__ __forceinline__ unsigned rowmin4_u32(unsigned x) {
    unsigned t;
    t = (unsigned)__builtin_amdgcn_update_dpp(-1, (int)x, 0x111, 0xF, 0xF, false); x = x < t ? x : t; // row_shr:1
    t = (unsigned)__builtin_amdgcn_update_dpp(-1, (int)x, 0x112, 0xF, 0xF, false); x = x < t ? x : t; // row_shr:2
    t = (unsigned)__builtin_amdgcn_update_dpp(-1, (int)x, 0x114, 0xF, 0xF, false); x = x < t ? x : t; // row_shr:4
    t = (unsigned)__builtin_amdgcn_update_dpp(-1, (int)x, 0x118, 0xF, 0xF, false); x = x < t ? x : t; // row_shr:8
    return x;
}

// wave-wide u32 min: 4 DPP steps, then 4 parallel readlanes + scalar min tree
// (R2/R4-validated: replaces the 2 row_bcast hops + lane-63 readlane; same value).
__device__ __forceinline__ unsigned wavemin_u32(unsigned x) {
    unsigned r = rowmin4_u32(x);
    unsigned a = (unsigned)__builtin_amdgcn_readlane((int)r, 15);
    unsigned b = (unsigned)__builtin_amdgcn_readlane((int)r, 31);
    unsigned c = (unsigned)__builtin_amdgcn_readlane((int)r, 47);
    unsigned d = (unsigned)__builtin_amdgcn_readlane((int)r, 63);
    return umin32(umin32(a, b), umin32(c, d));   // uniform -> s_min_u32
}

__device__ __forceinline__ float readlanef(float v, int l) {
    return __int_as_float(__builtin_amdgcn_readlane(__float_as_int(v), l));
}

// In-walk sweep over NS live slots (NS = ceil(cnt_c/64), dispatched per walk).
// Slots >= NS hold reload-time poison (ss -> +inf) and are never examined.
template<int NS>
__device__ __forceinline__ void sweep_step(const float (&sxr)[NSL], const float (&syr)[NSL],
                                           const float (&szr)[NSL], const unsigned (&mmr)[NSL],
                                           float pcx, float pcy, float pcz,
                                           unsigned &kbest, unsigned &mbest,
                                           float &bx, float &by, float &bz)
{
    float ss[NS];
    #pragma unroll
    for (int i = 0; i < NS; ++i) {
        float dx = pcx - sxr[i], dy = pcy - syr[i], dz = pcz - szr[i];
        ss[i] = (dx*dx + dy*dy) + dz*dz;   // ref order, contract off
    }
    float m;
    if constexpr (NS == 5)
        m = fminf(fminf(fminf(ss[0], ss[1]), fminf(ss[2], ss[3])), ss[4]);
    else if constexpr (NS == 6)
        m = fminf(fminf(fminf(ss[0], ss[1]), fminf(ss[2], ss[3])), fminf(ss[4], ss[5]));
    else
        m = fminf(fminf(fminf(ss[0], ss[1]), fminf(ss[2], ss[3])),
                  fminf(fminf(ss[4], ss[5]), fminf(ss[6], ss[7])));
    kbest = __float_as_uint(m);            // nonneg floats: bits order == value order
    unsigned mb = 0xFFFFFFFFu;
    #pragma unroll
    for (int i = 0; i < NS; ++i) {
        unsigned ci = (ss[i] == m) ? mmr[i] : 0xFFFFFFFFu;
        mb = umin32(mb, ci);
    }
    mbest = mb;
    bx = sxr[0]; by = syr[0]; bz = szr[0];
    #pragma unroll
    for (int i = 1; i < NS; ++i) {         // metas unique (sentinel != any winner)
        bool w = (mmr[i] == mb);
        bx = w ? sxr[i] : bx; by = w ? syr[i] : by; bz = w ? szr[i] : bz;
    }
}

template<int NS>
__device__ __forceinline__ void poison_step(float (&sxr)[NSL], const unsigned (&mmr)[NSL],
                                            unsigned wm)
{
    #pragma unroll
    for (int i = 0; i < NS; ++i)
        if (mmr[i] == wm) sxr[i] = 3e19f;  // poisoned slot: ss -> +inf
}

// One in-walk iteration + tail, single basic block in the common path.
// R5: (1) centre divides hoisted to body top (sx/scnt from carried sums; first
// iter of a walk gives x/1.0 == x bitwise, matching the old explicit init) so
// their latency hides under sweep+wavemin; (2) exact-key-tie second wavemin
// behind a rare uniform branch (single-candidate common path: that lane's mbest
// IS the min-meta tie-break); (3) unroll 4 for cross-iteration overlap.
#define WALK_INNER(NS)                                                          \
    _Pragma("unroll 4")                                                         \
    for (int k = 0; k < iters; ++k) {                                           \
        float icx = sx / scnt, icy = sy / scnt, icz = sz / scnt;                \
        unsigned kbest, mbest; float bx, by, bz;                                \
        sweep_step<NS>(sxr, syr, szr, mmr, pcx, pcy, pcz, kbest, mbest, bx, by, bz); \
        unsigned wk = wavemin_u32(kbest);                                       \
        bool cand = (kbest == wk);                                              \
        unsigned long long msk = __ballot(cand);                                \
        if (msk & (msk - 1)) {                   /* exact-bit key tie: rare */  \
            unsigned wm2 = wavemin_u32(cand ? mbest : 0xFFFFFFFFu);             \
            msk = __ballot(cand && (mbest == wm2));                             \
        }                                                                       \
        int wl = __ffsll((unsigned long long)msk) - 1;                          \
        unsigned wm = (unsigned)__builtin_amdgcn_readlane((int)mbest, wl);      \
        float pix = readlanef(bx, wl), piy = readlanef(by, wl), piz = readlanef(bz, wl); \
        pos = (int)(wm & 0xFFFu);                                               \
        poison_step<NS>(sxr, mmr, wm);                                          \
        float dx = pcx - pix, dy = pcy - piy, dz = pcz - piz;                   \
        bool a1 = (fabsf(dx) > amdxy_c) | (fabsf(dy) > amdxy_c) | (fabsf(dz) > amdz_c); \
        float ex = icx - pix, ey = icy - piy, ez = icz - piz;                   \
        float seC = (ex*ex + ey*ey) + ez*ez;                                    \
        bool nc = a1 | (wk > Vc) | (__float_as_uint(seC) > Vc);                 \
        lab += (int)nc;                                                         \
        su = nc ? u : su;                                                       \
        *((lane == 0) ? &startv[lab] : &sdump[lane]) = (unsigned short)su;      \
        scnt = nc ? 1.0f : (scnt + 1.0f);                                       \
        sx = nc ? pix : (sx + pix);                                             \
        sy = nc ? piy : (sy + piy);                                             \
        sz = nc ? piz : (sz + piz);                                             \
        capv = (lane == (u & 63)) ? (unsigned)pos : capv;                       \
        vor16[(u & ~63) + lane] = (unsigned short)capv;                         \
        pcx = pix; pcy = piy; pcz = piz;                                        \
        ++u;                                                                    \
    }

__global__ __launch_bounds__(BLK)
void frustum_cluster(const float* __restrict__ pts,
                     const int* __restrict__ lblg,
                     const float* __restrict__ anch,
                     int* __restrict__ out,
                     int* __restrict__ ws)
{
    const int tid  = threadIdx.x;
    const int lane = tid & 63;
    const int wid  = tid >> 6;

    // ---------------- global workspace ----------------
    int*    dlg    = ws + 16;                          // 3072 ints: per-point label
    float4* gstats = (float4*)(ws + 8192);             // per-cluster stats

    // ---------------- LDS ----------------
    __shared__ float4 gpts[NPTS];                      // class-grouped points; epilogue: ordered clusters
    __shared__ unsigned short vor16[NPTS];             // visit order; epilogue: bucket counts
    __shared__ unsigned short startv[NPTS];            // run starts; epilogue: bucket ids, then remap16
    __shared__ unsigned short sdump[64];               // dummy target for predicated startv writes
    __shared__ float amdxy[NCLS], amdz[NCLS];
    __shared__ unsigned vthr[NCLS], wthr[NCLS];        // sqrt-free compare thresholds
    __shared__ int cntL[NCLS], curL[NCLS], baseL[NCLS];
    __shared__ int cntC[NCLS], curC[NCLS], baseC[NCLS];
    __shared__ int p0s, nclusS;

    if (tid < NCLS) {
        float l = anch[tid*3+0], w = anch[tid*3+1], h = anch[tid*3+2];
        amdxy[tid] = fmaxf(l, w);
        amdz[tid]  = h;
        float r2 = sqrtf((l*l + w*w) + h*h) * 0.5f;    // norm(anchor)/2, ref op order
        // V: largest float bits v with sqrtf(v) <= r2  =>  (sqrtf(s) > r2) == (bits(s) > V)
        unsigned lo = 0u, hi = 0x7F7FFFFFu;
        while (hi - lo > 1u) {
            unsigned mid = lo + ((hi - lo) >> 1);
            if (sqrtf(__uint_as_float(mid)) <= r2) lo = mid; else hi = mid;
        }
        vthr[tid] = lo;
        // W: largest float bits w with sqrtf(w) < r2  =>  (sqrtf(s) < r2) == (bits(s) <= W)
        lo = 0u; hi = 0x7F7FFFFFu;
        while (hi - lo > 1u) {
            unsigned mid = lo + ((hi - lo) >> 1);
            if (sqrtf(__uint_as_float(mid)) < r2) lo = mid; else hi = mid;
        }
        wthr[tid] = lo;
        cntL[tid] = 0; curL[tid] = 0; cntC[tid] = 0; curC[tid] = 0;
    }
    __syncthreads();
    for (int j = tid; j < NPTS; j += BLK) atomicAdd(&cntL[lblg[j]], 1);
    __syncthreads();
    if (tid == 0) { int acc = 0; for (int c = 0; c < NCLS; ++c) { baseL[c] = acc; acc += cntL[c]; } }
    __syncthreads();
    // scatter into class-grouped layout; w = prebaked meta (id<<16 | cls<<12 | pos)
    for (int j = tid; j < NPTS; j += BLK) {
        int c = lblg[j];
        int pos = baseL[c] + atomicAdd(&curL[c], 1);
        float4 e;
        e.x = pts[3*j]; e.y = pts[3*j+1]; e.z = pts[3*j+2];
        e.w = __uint_as_float(((unsigned)j << 16) | ((unsigned)c << 12) | (unsigned)pos);
        gpts[pos] = e;
        if (j == 0) p0s = pos;
    }
    if (tid == 0) startv[0] = 0;
    __syncthreads();   // scatter + p0s visible; waves 1-3 fall through to the join barrier

    // ================= single-wave scan: wave 0, ZERO barriers =================
    if (wid == 0) {
        // lane-parked class constants (readlane fetch at walk start only)
        float axyL = 0.f, azL = 0.f; int vLn = 0, baseLn = 0, cntLn = 0;
        if (lane < NCLS) {
            axyL = amdxy[lane]; azL = amdz[lane];
            vLn = (int)vthr[lane]; baseLn = baseL[lane]; cntLn = cntL[lane];
        }
        const int p0 = p0s;
        int pos = p0;
        int cls = lblg[0];
        unsigned walked = 1u << cls;
        // slot registers (class points, loop-invariant within a walk); poison x=3e19 -> ss=+inf
        float sxr[NSL], syr[NSL], szr[NSL];
        unsigned mmr[NSL];
        float pcx = pts[0], pcy = pts[1], pcz = pts[2];
        float sx = pcx, sy = pcy, sz = pcz, scnt = 1.0f;
        int lab = 0;
        int su  = 0;                                   // running cluster-start visit index
        // visit-order capture: lane (u&63) holds pos of visit u; row written every iter
        // (final write of a row is the complete one). lane-0 init = p0 covers visit 0.
        unsigned capv = (unsigned)p0;
        int u = 1;                                     // next visit index

        for (int wix = 0; wix < NCLS; ++wix) {         // max 10 walks
            // ---- walk reload: class cls, excluding current pos ----
            int base_c = __builtin_amdgcn_readlane(baseLn, cls);
            int cnt_c  = __builtin_amdgcn_readlane(cntLn, cls);
            #pragma unroll
            for (int i = 0; i < NSL; ++i) {            // full 8: slots >= nsC stay poisoned
                int off = lane + (i << 6);
                int p = base_c + off;
                bool in = off < cnt_c;
                float4 e = gpts[in ? p : 0];
                bool v = in && (p != pos);             // fresh class: only current point visited
                sxr[i] = v ? e.x : 3e19f;              // poisoned slot: ss -> +inf
                syr[i] = v ? e.y : 0.f;
                szr[i] = v ? e.z : 0.f;
                // R13 BUGFIX: dead slots carry sentinel meta (never matches a winner)
                mmr[i] = in ? __float_as_uint(e.w) : 0xFFFFFFFFu;
            }
            float amdxy_c = readlanef(axyL, cls), amdz_c = readlanef(azL, cls);
            unsigned Vc = (unsigned)__builtin_amdgcn_readlane(vLn, cls);
            int nsC = (cnt_c + 63) >> 6;               // live slots this walk (5 for ~307-pt classes)
            int iters = cnt_c - 1;

            // ---- inner loop: single-block branchless iterations ----
            if (nsC <= 5)      { WALK_INNER(5) }
            else if (nsC == 6) { WALK_INNER(6) }
            else               { WALK_INNER(8) }

            if (u >= NPTS) break;

            // ---- fallback (9x total): nearest point of any un-walked class ----
            {
                unsigned kbest = 0xFFFFFFFFu, mbest = 0xFFFFFFFFu;
                float bx = 0.f, by = 0.f, bz = 0.f;
                for (int k2 = 0; k2 < NKB; ++k2) {
                    int p = lane + (k2 << 6);
                    float4 e = gpts[p];
                    unsigned meta = __float_as_uint(e.w);
                    float dx = pcx - e.x, dy = pcy - e.y, dz = pcz - e.z;
                    float s = (dx*dx + dy*dy) + dz*dz;
                    unsigned key = __float_as_uint(s);
                    bool ok = !((walked >> ((meta >> 12) & 15u)) & 1u);
                    if (ok && (key < kbest || (key == kbest && meta < mbest))) {
                        kbest = key; mbest = meta; bx = e.x; by = e.y; bz = e.z;
                    }
                }
                unsigned wk = wavemin_u32(kbest);
                bool cand = (kbest == wk);
                unsigned wm = wavemin_u32(cand ? mbest : 0xFFFFFFFFu);
                unsigned long long msk = __ballot(cand && (mbest == wm));
                int wl = __ffsll((unsigned long long)msk) - 1;
                float pix = readlanef(bx, wl), piy = readlanef(by, wl), piz = readlanef(bz, wl);
                pos = (int)(wm & 0xFFFu);
                cls = (int)((wm >> 12) & 15u);
                walked |= 1u << cls;
                // nc == true tail (new cluster, new class)
                lab += 1;
                su = u;
                if (lane == 0) startv[lab] = (unsigned short)u;
                sx = pix; sy = piy; sz = piz; scnt = 1.0f;
                capv = (lane == (u & 63)) ? (unsigned)pos : capv;
                vor16[(u & ~63) + lane] = (unsigned short)capv;
                pcx = pix; pcy = piy; pcz = piz;
                ++u;
            }
        }
        if (lane == 0) nclusS = lab;
    }
    __syncthreads();   // join: waves 1-3 parked here during the scan
    const int nclus = nclusS;

    // ---------------- epilogue (R11/R12-proven, unchanged; gpts untouched by scan) ----------------
    // (a) runs in visit order -> per-cluster stats (bitwise == scan's incremental sums) + dl to global
    for (int c2 = tid; c2 <= nclus; c2 += BLK) {
        int s0 = startv[c2];
        int s1e = (c2 < nclus) ? (int)startv[c2+1] : NPTS;
        float ax = 0.f, ay = 0.f, az = 0.f;
        int clsF = 0;
        for (int s = s0; s < s1e; ++s) {
            float4 e = gpts[vor16[s]];
            unsigned pk = __float_as_uint(e.w);
            if (s == s0) clsF = (int)((pk >> 12) & 15u);
            ax = ax + e.x; ay = ay + e.y; az = az + e.z;
            dlg[pk >> 16] = c2;
        }
        if (c2 < nclus) {
            float fc = (float)(s1e - s0);
            float4 g;
            g.x = ax / fc; g.y = ay / fc; g.z = az / fc;
            g.w = __uint_as_float(((unsigned)(s1e - s0) << 4) | (unsigned)clsF);
            gstats[c2] = g;
        }
    }
    __syncthreads();

    // (a2) bucket counts per class over clusters
    for (int c2 = tid; c2 < nclus; c2 += BLK)
        atomicAdd(&cntC[__float_as_uint(gstats[c2].w) & 15u], 1);
    __syncthreads();
    if (tid == 0) { int acc = 0; for (int c = 0; c < NCLS; ++c) { baseC[c] = acc; acc += cntC[c]; } }
    __syncthreads();

    // (b) scatter clusters into class buckets (vor16 = count, startv = cluster id)
    for (int c2 = tid; c2 < nclus; c2 += BLK) {
        unsigned gw = __float_as_uint(gstats[c2].w);
        int cl = (int)(gw & 15u);
        int slot = baseC[cl] + atomicAdd(&curC[cl], 1);
        vor16[slot]  = (unsigned short)(gw >> 4);
        startv[slot] = (unsigned short)c2;
    }
    __syncthreads();

    // (c) class-local stable rank (counts desc, id asc) -> ordered bucket entries in gpts
    for (int slot = tid; slot < nclus; slot += BLK) {
        int cl = 0;
        #pragma unroll
        for (int q = 1; q < NCLS; ++q) cl += (int)(slot >= baseC[q]);
        int b0 = baseC[cl], b1 = b0 + cntC[cl];
        int cnt = (int)vor16[slot], id = (int)startv[slot];
        int r = 0;
        for (int s2 = b0; s2 < b1; ++s2) {
            int cnt2 = (int)vor16[s2], id2 = (int)startv[s2];
            r += (int)((cnt2 > cnt) || (cnt2 == cnt && id2 < id));
        }
        float4 g = gstats[id];
        float4 oe;
        oe.x = g.x; oe.y = g.y; oe.z = g.z;
        oe.w = __uint_as_float(((unsigned)id << 1) | 1u);   // id | kept-bit (class implicit)
        gpts[b0 + r] = oe;
    }
    __syncthreads();

    // (d) remap16 identity (startv reused)
    unsigned short* remap16 = startv;
    for (int c2 = tid; c2 < NPTS; c2 += BLK) remap16[c2] = (unsigned short)c2;
    __syncthreads();

    // (e) per-class merge: classes independent; wave w handles classes w, w+4, w+8 — zero barriers
    for (int cl = wid; cl < NCLS; cl += NW) {
        int b0 = baseC[cl], b1 = b0 + cntC[cl];
        unsigned Wc = wthr[cl];
        for (int i = b0; i < b1; ++i) {
            float4 ei = gpts[i];
            unsigned wi = __float_as_uint(ei.w);
            if (wi & 1u) {                             // kept -> active absorber
                int orgI = (int)(wi >> 1);
                for (int j = i + 1 + lane; j < b1; j += 64) {
                    float4 ej = gpts[j];
                    unsigned wj = __float_as_uint(ej.w);
                    if (wj & 1u) {
                        float ddx = ej.x - ei.x, ddy = ej.y - ei.y, ddz = ej.z - ei.z;
                        float sdd = (ddx*ddx + ddy*ddy) + ddz*ddz;
                        if (__float_as_uint(sdd) <= Wc) {   // == (sqrtf(sdd) < r2_cl)
                            gpts[j].w = __uint_as_float(wj & ~1u);
                            remap16[wj >> 1] = (unsigned short)orgI;
                        }
                    }
                }
            }
        }
    }
    __syncthreads();

    // (f) final relabel
    for (int p = tid; p < NPTS; p += BLK) out[p] = (int)remap16[dlg[p]];
}

extern "C" void kernel_launch(void* const* d_in, const int* in_sizes, int n_in,
                              void* d_out, int out_size, void* d_ws, size_t ws_size,
                              hipStream_t stream) {
    const float* pts  = (const float*)d_in[0];   // [3072,3] f32
    const int*   lbl  = (const int*)d_in[1];     // [3072] i32
    const float* anch = (const float*)d_in[2];   // [10,3] f32
    frustum_cluster<<<dim3(1), dim3(BLK), 0, stream>>>(pts, lbl, anch,
                                                       (int*)d_out, (int*)d_ws);
}

// Round 6
// 1807.226 us; speedup vs baseline: 1.5844x; 1.2478x over previous
//
#include <hip/hip_runtime.h>
#include <math.h>

#define NPTS 3072
#define BLK  256
#define NW   4
#define NSL  8          // slots per lane: 8*64 = 512 >= max class size (~307+-17, +12 sigma)
#define NKB  48         // fallback batches: 48*64 = 3072
#define NCLS 10

#pragma clang fp contract(off)

__device__ __forceinline__ unsigned umin32(unsigned a, unsigned b) { return a < b ? a : b; }

// 4-step DPP row_shr chain: lanes 15/31/47/63 end with the min of their 16-lane row.
__device__ __forceinline__ unsigned rowmin4_u32(unsigned x) {
    unsigned t;
    t = (unsigned)__builtin_amdgcn_update_dpp(-1, (int)x, 0x111, 0xF, 0xF, false); x = x < t ? x : t; // row_shr:1
    t = (unsigned)__builtin_amdgcn_update_dpp(-1, (int)x, 0x112, 0xF, 0xF, false); x = x < t ? x : t; // row_shr:2
    t = (unsigned)__builtin_amdgcn_update_dpp(-1, (int)x, 0x114, 0xF, 0xF, false); x = x < t ? x : t; // row_shr:4
    t = (unsigned)__builtin_amdgcn_update_dpp(-1, (int)x, 0x118, 0xF, 0xF, false); x = x < t ? x : t; // row_shr:8
    return x;
}

// wave-wide u32 min: 4 DPP steps, then 4 parallel readlanes + scalar min tree (R2/R4-validated).
__device__ __forceinline__ unsigned wavemin_u32(unsigned x) {
    unsigned r = rowmin4_u32(x);
    unsigned a = (unsigned)__builtin_amdgcn_readlane((int)r, 15);
    unsigned b = (unsigned)__builtin_amdgcn_readlane((int)r, 31);
    unsigned c = (unsigned)__builtin_amdgcn_readlane((int)r, 47);
    unsigned d = (unsigned)__builtin_amdgcn_readlane((int)r, 63);
    return umin32(umin32(a, b), umin32(c, d));
}

__device__ __forceinline__ float readlanef(float v, int l) {
    return __int_as_float(__builtin_amdgcn_readlane(__float_as_int(v), l));
}

// In-walk sweep over NS live slots (NS = ceil(cnt_c/64), dispatched per walk).
template<int NS>
__device__ __forceinline__ void sweep_step(const float (&sxr)[NSL], const float (&syr)[NSL],
                                           const float (&szr)[NSL], const unsigned (&mmr)[NSL],
                                           float pcx, float pcy, float pcz,
                                           unsigned &kbest, unsigned &mbest,
                                           float &bx, float &by, float &bz)
{
    float ss[NS];
    #pragma unroll
    for (int i = 0; i < NS; ++i) {
        float dx = pcx - sxr[i], dy = pcy - syr[i], dz = pcz - szr[i];
        ss[i] = (dx*dx + dy*dy) + dz*dz;   // ref order, contract off
    }
    float m;
    if constexpr (NS == 5)
        m = fminf(fminf(fminf(ss[0], ss[1]), fminf(ss[2], ss[3])), ss[4]);
    else if constexpr (NS == 6)
        m = fminf(fminf(fminf(ss[0], ss[1]), fminf(ss[2], ss[3])), fminf(ss[4], ss[5]));
    else
        m = fminf(fminf(fminf(ss[0], ss[1]), fminf(ss[2], ss[3])),
                  fminf(fminf(ss[4], ss[5]), fminf(ss[6], ss[7])));
    kbest = __float_as_uint(m);            // nonneg floats: bits order == value order
    unsigned mb = 0xFFFFFFFFu;
    #pragma unroll
    for (int i = 0; i < NS; ++i) {
        unsigned ci = (ss[i] == m) ? mmr[i] : 0xFFFFFFFFu;
        mb = umin32(mb, ci);
    }
    mbest = mb;
    bx = sxr[0]; by = syr[0]; bz = szr[0];
    #pragma unroll
    for (int i = 1; i < NS; ++i) {         // metas unique (sentinel != any winner)
        bool w = (mmr[i] == mb);
        bx = w ? sxr[i] : bx; by = w ? syr[i] : by; bz = w ? szr[i] : bz;
    }
}

template<int NS>
__device__ __forceinline__ void poison_step(float (&sxr)[NSL], const unsigned (&mmr)[NSL],
                                            unsigned wm)
{
    #pragma unroll
    for (int i = 0; i < NS; ++i)
        if (mmr[i] == wm) sxr[i] = 3e19f;  // poisoned slot: ss -> +inf
}

// R6 phase-A inner iteration: argmin core ONLY (diag-core-equivalent) + pos record.
// All cluster bookkeeping (nc, centres, labels) moved to phase B (walk replay).
#define WALK_INNER(NS)                                                          \
    _Pragma("unroll 4")                                                         \
    for (int k = 0; k < iters; ++k) {                                           \
        unsigned kbest, mbest; float bx, by, bz;                                \
        sweep_step<NS>(sxr, syr, szr, mmr, pcx, pcy, pcz, kbest, mbest, bx, by, bz); \
        unsigned wk = wavemin_u32(kbest);                                       \
        bool cand = (kbest == wk);                                              \
        unsigned long long msk = __ballot(cand);                                \
        if (msk & (msk - 1)) {                   /* exact-bit key tie: rare */  \
            unsigned wm2 = wavemin_u32(cand ? mbest : 0xFFFFFFFFu);             \
            msk = __ballot(cand && (mbest == wm2));                             \
        }                                                                       \
        int wl = __ffsll((unsigned long long)msk) - 1;                          \
        unsigned wm = (unsigned)__builtin_amdgcn_readlane((int)mbest, wl);      \
        float pix = readlanef(bx, wl), piy = readlanef(by, wl), piz = readlanef(bz, wl); \
        pos = (int)(wm & 0xFFFu);                                               \
        poison_step<NS>(sxr, mmr, wm);                                          \
        *((lane == 0) ? &recM16[u] : &sdump[lane]) = (unsigned short)pos;       \
        pcx = pix; pcy = piy; pcz = piz;                                        \
        ++u;                                                                    \
    }

__global__ __launch_bounds__(BLK)
void frustum_cluster(const float* __restrict__ pts,
                     const int* __restrict__ lblg,
                     const float* __restrict__ anch,
                     int* __restrict__ out,
                     int* __restrict__ ws)
{
    const int tid  = threadIdx.x;
    const int lane = tid & 63;
    const int wid  = tid >> 6;

    // ---------------- global workspace ----------------
    int*    dlg    = ws + 16;                          // 3072 ints: per-point label
    float4* gstats = (float4*)(ws + 8192);             // per-cluster stats

    // ---------------- LDS (~62 KB) ----------------
    __shared__ float4 gpts[NPTS];                      // class-grouped points; epilogue: ordered clusters
    __shared__ unsigned short recM16[NPTS];            // visit order -> pos (A writes, B+(a) read; (b)/(c): counts scratch)
    __shared__ unsigned short startv[NPTS];            // cluster starts (B stages+compacts); (b)/(c): ids; (d)-(f): remap16
    __shared__ unsigned short sdump[64];               // dummy target for predicated writes
    __shared__ unsigned short walkS16[65];             // walk w's first visit index (fallback record); NPTS = absent
    __shared__ unsigned short walkCls16[16];           // walk w's class
    __shared__ float amdxy[NCLS], amdz[NCLS];
    __shared__ unsigned vthr[NCLS], wthr[NCLS];        // sqrt-free compare thresholds
    __shared__ int cntL[NCLS], curL[NCLS], baseL[NCLS];
    __shared__ int cntC[NCLS], curC[NCLS], baseC[NCLS];
    __shared__ int cntW[16], baseW[16];                // clusters per walk / prefix
    __shared__ int p0s, nclusS;

    if (tid < NCLS) {
        float l = anch[tid*3+0], w = anch[tid*3+1], h = anch[tid*3+2];
        amdxy[tid] = fmaxf(l, w);
        amdz[tid]  = h;
        float r2 = sqrtf((l*l + w*w) + h*h) * 0.5f;    // norm(anchor)/2, ref op order
        // V: largest float bits v with sqrtf(v) <= r2  =>  (sqrtf(s) > r2) == (bits(s) > V)
        unsigned lo = 0u, hi = 0x7F7FFFFFu;
        while (hi - lo > 1u) {
            unsigned mid = lo + ((hi - lo) >> 1);
            if (sqrtf(__uint_as_float(mid)) <= r2) lo = mid; else hi = mid;
        }
        vthr[tid] = lo;
        // W: largest float bits w with sqrtf(w) < r2  =>  (sqrtf(s) < r2) == (bits(s) <= W)
        lo = 0u; hi = 0x7F7FFFFFu;
        while (hi - lo > 1u) {
            unsigned mid = lo + ((hi - lo) >> 1);
            if (sqrtf(__uint_as_float(mid)) < r2) lo = mid; else hi = mid;
        }
        wthr[tid] = lo;
        cntL[tid] = 0; curL[tid] = 0; cntC[tid] = 0; curC[tid] = 0;
    }
    if (tid < 65) walkS16[tid] = (unsigned short)NPTS;
    if (tid < 16) { walkCls16[tid] = 0; cntW[tid] = 0; }
    __syncthreads();
    for (int j = tid; j < NPTS; j += BLK) atomicAdd(&cntL[lblg[j]], 1);
    __syncthreads();
    if (tid == 0) { int acc = 0; for (int c = 0; c < NCLS; ++c) { baseL[c] = acc; acc += cntL[c]; } }
    __syncthreads();
    // scatter into class-grouped layout; w = prebaked meta (id<<16 | cls<<12 | pos)
    for (int j = tid; j < NPTS; j += BLK) {
        int c = lblg[j];
        int pos = baseL[c] + atomicAdd(&curL[c], 1);
        float4 e;
        e.x = pts[3*j]; e.y = pts[3*j+1]; e.z = pts[3*j+2];
        e.w = __uint_as_float(((unsigned)j << 16) | ((unsigned)c << 12) | (unsigned)pos);
        gpts[pos] = e;
        if (j == 0) p0s = pos;
    }
    __syncthreads();   // scatter + p0s visible

    // ================= PHASE A: single-wave argmin walk (wave 0) =================
    if (wid == 0) {
        int baseLn = 0, cntLn = 0;
        if (lane < NCLS) { baseLn = baseL[lane]; cntLn = cntL[lane]; }
        const int p0 = p0s;
        int pos = p0;
        int cls = lblg[0];
        unsigned walked = 1u << cls;
        float sxr[NSL], syr[NSL], szr[NSL];
        unsigned mmr[NSL];
        float pcx = pts[0], pcy = pts[1], pcz = pts[2];
        int u = 1;                                     // next visit index
        if (lane == 0) recM16[0] = (unsigned short)p0;

        for (int wix = 0; wix < NCLS; ++wix) {         // max 10 walks
            if (lane == 0) {                           // walk boundary record
                walkS16[wix]   = (unsigned short)(u - 1);   // wix=0: 0 (visit 0); else fallback rec idx
                walkCls16[wix] = (unsigned short)cls;
            }
            // ---- walk reload: class cls, excluding current pos ----
            int base_c = __builtin_amdgcn_readlane(baseLn, cls);
            int cnt_c  = __builtin_amdgcn_readlane(cntLn, cls);
            #pragma unroll
            for (int i = 0; i < NSL; ++i) {            // full 8: slots >= nsC stay poisoned
                int off = lane + (i << 6);
                int p = base_c + off;
                bool in = off < cnt_c;
                float4 e = gpts[in ? p : 0];
                bool v = in && (p != pos);             // fresh class: only current point visited
                sxr[i] = v ? e.x : 3e19f;
                syr[i] = v ? e.y : 0.f;
                szr[i] = v ? e.z : 0.f;
                mmr[i] = in ? __float_as_uint(e.w) : 0xFFFFFFFFu;  // sentinel meta for dead slots
            }
            int nsC = (cnt_c + 63) >> 6;
            int iters = cnt_c - 1;

            if (nsC <= 5)      { WALK_INNER(5) }
            else if (nsC == 6) { WALK_INNER(6) }
            else               { WALK_INNER(8) }

            if (u >= NPTS) break;

            // ---- fallback (9x total): nearest point of any un-walked class ----
            {
                unsigned kbest = 0xFFFFFFFFu, mbest = 0xFFFFFFFFu;
                float bx = 0.f, by = 0.f, bz = 0.f;
                for (int k2 = 0; k2 < NKB; ++k2) {
                    int p = lane + (k2 << 6);
                    float4 e = gpts[p];
                    unsigned meta = __float_as_uint(e.w);
                    float dx = pcx - e.x, dy = pcy - e.y, dz = pcz - e.z;
                    float s = (dx*dx + dy*dy) + dz*dz;
                    unsigned key = __float_as_uint(s);
                    bool ok = !((walked >> ((meta >> 12) & 15u)) & 1u);
                    if (ok && (key < kbest || (key == kbest && meta < mbest))) {
                        kbest = key; mbest = meta; bx = e.x; by = e.y; bz = e.z;
                    }
                }
                unsigned wk = wavemin_u32(kbest);
                bool cand = (kbest == wk);
                unsigned wm = wavemin_u32(cand ? mbest : 0xFFFFFFFFu);
                unsigned long long msk = __ballot(cand && (mbest == wm));
                int wl = __ffsll((unsigned long long)msk) - 1;
                float pix = readlanef(bx, wl), piy = readlanef(by, wl), piz = readlanef(bz, wl);
                pos = (int)(wm & 0xFFFu);
                cls = (int)((wm >> 12) & 15u);
                walked |= 1u << cls;
                *((lane == 0) ? &recM16[u] : &sdump[lane]) = (unsigned short)pos;
                pcx = pix; pcy = piy; pcz = piz;
                ++u;
            }
        }
    }
    __syncthreads();   // join A

    // ================= PHASE B: lane-parallel walk replay (wave 0) =================
    // Lane w replays walk w (<=10 active lanes), recomputing nc bitwise-identically:
    // seS bits == A's winner key (same gpts-sourced operands, same op order, contract off);
    // seC from carried sums with top-of-iter div (x/1.0 exact at cluster start).
    // Cluster-start visit indices staged into startv[s_w + j] (disjoint per walk).
    if (wid == 0) {
        int w = lane;
        int sW = (int)walkS16[w];                      // NPTS if absent (w >= #walks)
        int eW = (int)walkS16[w + 1];
        bool exists = sW < NPTS;
        int cls = (int)walkCls16[exists ? w : 0];
        float axy = amdxy[cls], az = amdz[cls];
        unsigned Vc = vthr[cls];
        int pos0 = (int)recM16[exists ? sW : 0];
        float4 pe = gpts[pos0];
        float prevx = pe.x, prevy = pe.y, prevz = pe.z;
        float sx = prevx, sy = prevy, sz = prevz, scnt = 1.0f;
        int cnt = 1;
        if (exists) startv[sW] = (unsigned short)sW;   // walk's first visit starts a cluster
        int u = sW + 1;
        int posn = (int)recM16[(exists && u < eW) ? u : 0];   // prefetched meta
        for (;;) {
            unsigned long long alive = __ballot(u < eW);
            if (!alive) break;
            bool act = (u < eW);
            float4 ec = gpts[act ? posn : 0];
            int posn2 = (int)recM16[(u + 1 < eW) ? (u + 1) : 0];
            float pix = ec.x, piy = ec.y, piz = ec.z;
            float dx = prevx - pix, dy = prevy - piy, dz = prevz - piz;
            float seS = (dx*dx + dy*dy) + dz*dz;       // == A's winner key bits
            bool a1 = (fabsf(dx) > axy) | (fabsf(dy) > axy) | (fabsf(dz) > az);
            float icx = sx / scnt, icy = sy / scnt, icz = sz / scnt;
            float ex = icx - pix, ey = icy - piy, ez = icz - piz;
            float seC = (ex*ex + ey*ey) + ez*ez;
            bool nc = a1 | (__float_as_uint(seS) > Vc) | (__float_as_uint(seC) > Vc);
            if (act & nc) startv[sW + cnt] = (unsigned short)u;
            cnt += (act & nc) ? 1 : 0;
            scnt = nc ? 1.0f : (scnt + 1.0f);          // scnt >= 1 always (no div-by-0)
            sx = nc ? pix : (sx + pix);
            sy = nc ? piy : (sy + piy);
            sz = nc ? piz : (sz + piz);
            prevx = pix; prevy = piy; prevz = piz;
            posn = posn2;
            ++u;
        }
        if (exists) cntW[w] = cnt;
    }
    __syncthreads();   // join B

    if (tid == 0) {    // prefix over per-walk cluster counts
        int acc = 0;
        for (int c = 0; c < NCLS; ++c) { baseW[c] = acc; acc += cntW[c]; }
        nclusS = acc - 1;                              // lab semantics: starts - 1
    }
    __syncthreads();

    // compaction: left-shift staged starts to global positions (walks in order; baseW[w] <= s_w
    // provably, so batched read-then-write never clobbers unread data)
    if (wid == 0) {
        for (int w2 = 0; w2 < NCLS; ++w2) {
            int sW = (int)walkS16[w2];
            if (sW >= NPTS) break;                     // walks contiguous from 0
            int bW = baseW[w2], cW = cntW[w2];
            if (bW == sW) continue;
            for (int j = lane; j < cW; j += 64) {
                unsigned short v = startv[sW + j];
                startv[bW + j] = v;
            }
        }
    }
    __syncthreads();
    const int nclus = nclusS;

    // ---------------- epilogue (R11/R12-proven; vor16 -> recM16 substitution only) ----------------
    // (a) runs in visit order -> per-cluster stats (bitwise == incremental sums) + dl to global
    for (int c2 = tid; c2 <= nclus; c2 += BLK) {
        int s0 = startv[c2];
        int s1e = (c2 < nclus) ? (int)startv[c2+1] : NPTS;
        float ax = 0.f, ay = 0.f, az = 0.f;
        int clsF = 0;
        for (int s = s0; s < s1e; ++s) {
            float4 e = gpts[recM16[s]];
            unsigned pk = __float_as_uint(e.w);
            if (s == s0) clsF = (int)((pk >> 12) & 15u);
            ax = ax + e.x; ay = ay + e.y; az = az + e.z;
            dlg[pk >> 16] = c2;
        }
        if (c2 < nclus) {
            float fc = (float)(s1e - s0);
            float4 g;
            g.x = ax / fc; g.y = ay / fc; g.z = az / fc;
            g.w = __uint_as_float(((unsigned)(s1e - s0) << 4) | (unsigned)clsF);
            gstats[c2] = g;
        }
    }
    __syncthreads();

    // (a2) bucket counts per class over clusters
    for (int c2 = tid; c2 < nclus; c2 += BLK)
        atomicAdd(&cntC[__float_as_uint(gstats[c2].w) & 15u], 1);
    __syncthreads();
    if (tid == 0) { int acc = 0; for (int c = 0; c < NCLS; ++c) { baseC[c] = acc; acc += cntC[c]; } }
    __syncthreads();

    // (b) scatter clusters into class buckets (recM16 = count, startv = cluster id)
    for (int c2 = tid; c2 < nclus; c2 += BLK) {
        unsigned gw = __float_as_uint(gstats[c2].w);
        int cl = (int)(gw & 15u);
        int slot = baseC[cl] + atomicAdd(&curC[cl], 1);
        recM16[slot] = (unsigned short)(gw >> 4);
        startv[slot] = (unsigned short)c2;
    }
    __syncthreads();

    // (c) class-local stable rank (counts desc, id asc) -> ordered bucket entries in gpts
    for (int slot = tid; slot < nclus; slot += BLK) {
        int cl = 0;
        #pragma unroll
        for (int q = 1; q < NCLS; ++q) cl += (int)(slot >= baseC[q]);
        int b0 = baseC[cl], b1 = b0 + cntC[cl];
        int cnt = (int)recM16[slot], id = (int)startv[slot];
        int r = 0;
        for (int s2 = b0; s2 < b1; ++s2) {
            int cnt2 = (int)recM16[s2], id2 = (int)startv[s2];
            r += (int)((cnt2 > cnt) || (cnt2 == cnt && id2 < id));
        }
        float4 g = gstats[id];
        float4 oe;
        oe.x = g.x; oe.y = g.y; oe.z = g.z;
        oe.w = __uint_as_float(((unsigned)id << 1) | 1u);   // id | kept-bit (class implicit)
        gpts[b0 + r] = oe;
    }
    __syncthreads();

    // (d) remap16 identity (startv reused)
    unsigned short* remap16 = startv;
    for (int c2 = tid; c2 < NPTS; c2 += BLK) remap16[c2] = (unsigned short)c2;
    __syncthreads();

    // (e) per-class merge: classes independent; wave w handles classes w, w+4, w+8 — zero barriers
    for (int cl = wid; cl < NCLS; cl += NW) {
        int b0 = baseC[cl], b1 = b0 + cntC[cl];
        unsigned Wc = wthr[cl];
        for (int i = b0; i < b1; ++i) {
            float4 ei = gpts[i];
            unsigned wi = __float_as_uint(ei.w);
            if (wi & 1u) {                             // kept -> active absorber
                int orgI = (int)(wi >> 1);
                for (int j = i + 1 + lane; j < b1; j += 64) {
                    float4 ej = gpts[j];
                    unsigned wj = __float_as_uint(ej.w);
                    if (wj & 1u) {
                        float ddx = ej.x - ei.x, ddy = ej.y - ei.y, ddz = ej.z - ei.z;
                        float sdd = (ddx*ddx + ddy*ddy) + ddz*ddz;
                        if (__float_as_uint(sdd) <= Wc) {   // == (sqrtf(sdd) < r2_cl)
                            gpts[j].w = __uint_as_float(wj & ~1u);
                            remap16[wj >> 1] = (unsigned short)orgI;
                        }
                    }
                }
            }
        }
    }
    __syncthreads();

    // (f) final relabel
    for (int p = tid; p < NPTS; p += BLK) out[p] = (int)remap16[dlg[p]];
}

extern "C" void kernel_launch(void* const* d_in, const int* in_sizes, int n_in,
                              void* d_out, int out_size, void* d_ws, size_t ws_size,
                              hipStream_t stream) {
    const float* pts  = (const float*)d_in[0];   // [3072,3] f32
    const int*   lbl  = (const int*)d_in[1];     // [3072] i32
    const float* anch = (const float*)d_in[2];   // [10,3] f32
    frustum_cluster<<<dim3(1), dim3(BLK), 0, stream>>>(pts, lbl, anch,
                                                       (int*)d_out, (int*)d_ws);
}